// Round 13
// baseline (368.503 us; speedup 1.0000x reference)
//
#include <hip/hip_runtime.h>

// SlotAttention MI355X v13 — v12 (349us) + R11's two correctness-proven wins,
// WITHOUT R11's fatal __launch_bounds__(256,4) (which forced VGPR=64 ->
// scratch spills): (a) LN fused into k2<DOLN=1> iteration 0 (reads f32 input,
// emits xln for iters 1-2; k1 deleted); (b) two-stage q (@Wq then @Wk^T; k0
// deleted). k2 keeps v12's swizzle + pair-folded partials.
// Workspace (~151.5 MiB): xln@0, qbuf@134217728, nump@134348800 (16.8MB),
//   denp@151126016, sbuf@151257088.

#define NTOT 16384
#define CDIM 128

using short8 = __attribute__((ext_vector_type(8))) short;
using f32x4  = __attribute__((ext_vector_type(4))) float;
using u32x2  = __attribute__((ext_vector_type(2))) unsigned;

__device__ __forceinline__ unsigned pkbf(float lo, float hi) {
  unsigned r;
  asm("v_cvt_pk_bf16_f32 %0, %1, %2" : "=v"(r) : "v"(lo), "v"(hi));
  return r;
}
__device__ __forceinline__ float sigf(float x) { return 1.f / (1.f + __expf(-x)); }
__device__ __forceinline__ float tanhfast(float x) {
  x = fminf(fmaxf(x, -15.f), 15.f);
  float e = __expf(2.f * x);
  return (e - 1.f) / (e + 1.f);
}

// ---- Kq: qa = ((LN_s(slots) @ Wq) @ Wk^T) / sqrt(C) -> bf16 [b][16][128] ----
__global__ __launch_bounds__(512) void kq_init(
    const float* __restrict__ slots, const float* __restrict__ lnsg,
    const float* __restrict__ lnsb, const float* __restrict__ Wq,
    const float* __restrict__ Wk, unsigned short* __restrict__ qout) {
  const int b = blockIdx.x, t = threadIdx.x;
  const int s = t >> 5, jq = (t & 31) * 4;
  __shared__ __align__(16) float lnq[2048];
  __shared__ __align__(16) float q1b[2048];
  f32x4 x4 = *(const f32x4*)(slots + b * 2048 + t * 4);
  float ps = x4[0] + x4[1] + x4[2] + x4[3];
  float pq = x4[0]*x4[0] + x4[1]*x4[1] + x4[2]*x4[2] + x4[3]*x4[3];
  ps += __shfl_xor(ps, 1); ps += __shfl_xor(ps, 2); ps += __shfl_xor(ps, 4); ps += __shfl_xor(ps, 8); ps += __shfl_xor(ps, 16);
  pq += __shfl_xor(pq, 1); pq += __shfl_xor(pq, 2); pq += __shfl_xor(pq, 4); pq += __shfl_xor(pq, 8); pq += __shfl_xor(pq, 16);
  float mean = ps * (1.f / 128.f);
  float var  = pq * (1.f / 128.f) - mean * mean;
  float rstd = rsqrtf(var + 1e-5f);
  f32x4 l4 = (x4 - mean) * rstd * (*(const f32x4*)(lnsg + jq)) + (*(const f32x4*)(lnsb + jq));
  *(f32x4*)(lnq + t * 4) = l4;
  __syncthreads();
  f32x4 q1 = {0.f, 0.f, 0.f, 0.f};
  const float* qrow = lnq + s * 128;
  for (int c = 0; c < 128; ++c)
    q1 += *(const f32x4*)(Wq + c * 128 + jq) * qrow[c];
  *(f32x4*)(q1b + t * 4) = q1;
  __syncthreads();
  const float* q1r = q1b + s * 128;
  f32x4 qa = {0.f, 0.f, 0.f, 0.f};
  for (int c2 = 0; c2 < 128; c2 += 4) {
    f32x4 qv = *(const f32x4*)(q1r + c2);
    #pragma unroll
    for (int i = 0; i < 4; ++i) {
      f32x4 wv = *(const f32x4*)(Wk + (jq + i) * 128 + c2);
      qa[i] += qv[0]*wv[0] + qv[1]*wv[1] + qv[2]*wv[2] + qv[3]*wv[3];
    }
  }
  qa *= 0.08838834764831845f;  // 1/sqrt(128)
  u32x2 pk = { pkbf(qa[0], qa[1]), pkbf(qa[2], qa[3]) };
  *(u32x2*)(qout + b * 2048 + t * 4) = pk;
}

// ---- K2: [optional LN from f32] dots -> softmax -> p @ xln, folded partials --
template<int DOLN>
__global__ __launch_bounds__(256) void k2_attn(
    const float* __restrict__ inputs, const float* __restrict__ gam,
    const float* __restrict__ bet, unsigned short* __restrict__ xln,
    const unsigned short* __restrict__ qm,
    float* __restrict__ nump, float* __restrict__ denp) {
  const int nb = blockIdx.x, b = blockIdx.y;
  const int t = threadIdx.x, w = t >> 6, l = t & 63, lr = l & 15, lg = l >> 4;
  // smem: xT 4x8192 | pbuf 4x1280 | gs/bs 1024
  __shared__ __align__(16) char smem[38912];
  char* xTc = smem + w * 8192;
  unsigned short* pbw = (unsigned short*)(smem + 32768) + w * 640;
  float* gs = (float*)(smem + 37888);
  float* bs = gs + 128;

  if (DOLN) {
    if (t < 128) { gs[t] = gam[t]; bs[t] = bet[t]; }
    __syncthreads();
  }

  unsigned short* xb = xln + (long)b * (NTOT * CDIM);
  const unsigned short* qb = qm + b * 2048;

  short8 qf[4];
  #pragma unroll
  for (int kk = 0; kk < 4; ++kk)
    qf[kk] = *(const short8*)(qb + lr * CDIM + kk * 32 + lg * 8);

  f32x4 acc[8];
  #pragma unroll
  for (int i = 0; i < 8; ++i) acc[i] = (f32x4){0.f, 0.f, 0.f, 0.f};
  f32x4 dacc = {0.f, 0.f, 0.f, 0.f};

  const int base_n = nb * 512 + w * 32;

  short8 xnext[8];
  if (!DOLN) {
    #pragma unroll
    for (int h = 0; h < 2; ++h)
      #pragma unroll
      for (int kk = 0; kk < 4; ++kk)
        xnext[h*4+kk] = *(const short8*)(xb + (long)(base_n + h*16 + lr) * CDIM + kk*32 + lg*8);
  }

  #pragma unroll
  for (int itt = 0; itt < 4; ++itt) {
    const int n0 = base_n + itt * 128;
    short8 xcur[8];
    if (DOLN) {
      // LN from f32 input: lane owns row n0+h*16+lr, cols kk*32+lg*8..+7
      #pragma unroll
      for (int h = 0; h < 2; ++h) {
        const float* src = inputs + ((long)b * NTOT + n0 + h * 16 + lr) * CDIM + lg * 8;
        f32x4 xx[4][2];
        #pragma unroll
        for (int kk = 0; kk < 4; ++kk) {
          xx[kk][0] = *(const f32x4*)(src + kk * 32);
          xx[kk][1] = *(const f32x4*)(src + kk * 32 + 4);
        }
        float s1 = 0.f, s2 = 0.f;
        #pragma unroll
        for (int kk = 0; kk < 4; ++kk)
          #pragma unroll
          for (int p = 0; p < 2; ++p)
            #pragma unroll
            for (int i = 0; i < 4; ++i) { float v = xx[kk][p][i]; s1 += v; s2 += v * v; }
        s1 += __shfl_xor(s1, 16); s1 += __shfl_xor(s1, 32);
        s2 += __shfl_xor(s2, 16); s2 += __shfl_xor(s2, 32);
        const float mean = s1 * (1.f / 128.f);
        const float rstd = rsqrtf(s2 * (1.f / 128.f) - mean * mean + 1e-5f);
        #pragma unroll
        for (int kk = 0; kk < 4; ++kk) {
          int c0 = kk * 32 + lg * 8;
          union { unsigned uw[4]; short8 s8; } cv;
          #pragma unroll
          for (int p = 0; p < 2; ++p) {
            float y0 = (xx[kk][p][0] - mean) * rstd * gs[c0 + p*4 + 0] + bs[c0 + p*4 + 0];
            float y1 = (xx[kk][p][1] - mean) * rstd * gs[c0 + p*4 + 1] + bs[c0 + p*4 + 1];
            float y2 = (xx[kk][p][2] - mean) * rstd * gs[c0 + p*4 + 2] + bs[c0 + p*4 + 2];
            float y3 = (xx[kk][p][3] - mean) * rstd * gs[c0 + p*4 + 3] + bs[c0 + p*4 + 3];
            cv.uw[p*2 + 0] = pkbf(y0, y1);
            cv.uw[p*2 + 1] = pkbf(y2, y3);
          }
          xcur[h*4+kk] = cv.s8;
          *(short8*)(xb + (long)(n0 + h*16 + lr) * CDIM + c0) = cv.s8;
        }
      }
    } else {
      #pragma unroll
      for (int r = 0; r < 8; ++r) xcur[r] = xnext[r];
      if (itt < 3) {
        const int n1 = base_n + (itt + 1) * 128;
        #pragma unroll
        for (int h = 0; h < 2; ++h)
          #pragma unroll
          for (int kk = 0; kk < 4; ++kk)
            xnext[h*4+kk] = *(const short8*)(xb + (long)(n1 + h*16 + lr) * CDIM + kk*32 + lg*8);
      }
    }

    // transpose tile into xT: byte(c,n) = c*64 + n*2, XOR key (((c>>1)^(c>>3))&3)<<4
    // write side (c = kk*32+lg*8+e): key = (((e>>1)&3) ^ lg) << 4
    #pragma unroll
    for (int r = 0; r < 8; ++r) {
      const int h = r >> 2, kk = r & 3;
      const unsigned wb = (unsigned)(kk * 2048 + lg * 512 + (h * 16 + lr) * 2);
      #pragma unroll
      for (int e = 0; e < 8; ++e) {
        unsigned key = ((((unsigned)e >> 1) & 3u) ^ (unsigned)lg) << 4;
        unsigned off = (wb + e * 64) ^ key;
        *(unsigned short*)(xTc + off) = (unsigned short)xcur[r][e];
      }
    }
    // dots D[s][n] per 16-n half
    #pragma unroll
    for (int h = 0; h < 2; ++h) {
      f32x4 d = {0.f, 0.f, 0.f, 0.f};
      #pragma unroll
      for (int kk = 0; kk < 4; ++kk)
        d = __builtin_amdgcn_mfma_f32_16x16x32_bf16(qf[kk], xcur[h*4+kk], d, 0, 0, 0);
      float e0 = __expf(d[0]), e1 = __expf(d[1]), e2 = __expf(d[2]), e3 = __expf(d[3]);
      float cs = e0 + e1 + e2 + e3;
      cs += __shfl_xor(cs, 16);
      cs += __shfl_xor(cs, 32);
      float inv = 1.f / cs;
      float p0 = e0 * inv + 1e-8f, p1 = e1 * inv + 1e-8f,
            p2 = e2 * inv + 1e-8f, p3 = e3 * inv + 1e-8f;
      dacc[0] += p0; dacc[1] += p1; dacc[2] += p2; dacc[3] += p3;
      unsigned w01 = pkbf(p0, p1), w23 = pkbf(p2, p3);
      const int nn = h * 16 + lr;
      pbw[(lg*4 + 0) * 40 + nn] = (unsigned short)w01;
      pbw[(lg*4 + 1) * 40 + nn] = (unsigned short)(w01 >> 16);
      pbw[(lg*4 + 2) * 40 + nn] = (unsigned short)w23;
      pbw[(lg*4 + 3) * 40 + nn] = (unsigned short)(w23 >> 16);
    }
    asm volatile("" ::: "memory");  // LDS writes before reads; same-wave DS in-order
    short8 pf = *(const short8*)(pbw + lr * 40 + lg * 8);
    #pragma unroll
    for (int ct = 0; ct < 8; ++ct) {
      // read side (c = ct*16+lr): key = ((lr>>1)&3) ^ ((ct*2 + (lr>>3))&3)
      unsigned key = (((((unsigned)lr >> 1) & 3u) ^
                      (((unsigned)(ct * 2) + ((unsigned)lr >> 3)) & 3u)) << 4);
      unsigned off = ((unsigned)((ct*16 + lr) * 64 + lg * 16)) ^ key;
      short8 af = *(const short8*)(xTc + off);
      acc[ct] = __builtin_amdgcn_mfma_f32_16x16x32_bf16(af, pf, acc[ct], 0, 0, 0);
    }
    asm volatile("" ::: "memory");  // WAR: next tile's xT writes after these reads
  }

  // den: reduce over n (lr lanes)
  #pragma unroll
  for (int m = 1; m <= 8; m <<= 1) {
    dacc[0] += __shfl_xor(dacc[0], m); dacc[1] += __shfl_xor(dacc[1], m);
    dacc[2] += __shfl_xor(dacc[2], m); dacc[3] += __shfl_xor(dacc[3], m);
  }
  __syncthreads();  // all waves done with xT/pbuf
  if (w >= 2) {
    float* rb = (float*)(smem + (w - 2) * 8192);
    #pragma unroll
    for (int ct = 0; ct < 8; ++ct)
      *(f32x4*)(rb + lr * 128 + ct * 16 + lg * 4) = acc[ct];
    if (lr == 0) {
      float* db = (float*)(smem + 32768) + (w - 2) * 16;
      #pragma unroll
      for (int r = 0; r < 4; ++r) db[lg * 4 + r] = dacc[r];
    }
  }
  __syncthreads();
  if (w < 2) {
    const float* rb = (float*)(smem + w * 8192);
    float* outp = nump + (((long)b * 32 + nb) * 2 + w) * 2048;
    #pragma unroll
    for (int ct = 0; ct < 8; ++ct) {
      f32x4 other = *(const f32x4*)(rb + lr * 128 + ct * 16 + lg * 4);
      *(f32x4*)(outp + lr * 128 + ct * 16 + lg * 4) = acc[ct] + other;  // [s][c]
    }
    if (lr == 0) {
      const float* db = (float*)(smem + 32768) + w * 16;
      #pragma unroll
      for (int r = 0; r < 4; ++r)
        denp[(((long)b * 32 + nb) * 2 + w) * 16 + lg * 4 + r] =
            dacc[r] + db[lg * 4 + r];
    }
  }
}

// ---- K3: reduce(64) -> /den -> @Wv -> GRU -> MLP -> slots (+ q next) ----
__global__ __launch_bounds__(128) void k3_update(
    const float* __restrict__ sprev, const float* __restrict__ nump,
    const float* __restrict__ denp, const float* __restrict__ Wv,
    const float* __restrict__ wih, const float* __restrict__ whh,
    const float* __restrict__ bih, const float* __restrict__ bhh,
    const float* __restrict__ w1, const float* __restrict__ b1,
    const float* __restrict__ w2, const float* __restrict__ b2,
    const float* __restrict__ lnfg, const float* __restrict__ lnfb,
    const float* __restrict__ lnsg, const float* __restrict__ lnsb,
    const float* __restrict__ Wq, const float* __restrict__ Wk,
    float* __restrict__ sout, unsigned short* __restrict__ qout, const int doq) {
  const int g = blockIdx.x, b = blockIdx.y, t = threadIdx.x;
  const int sl = t >> 5, jq = (t & 31) * 4;
  const int s = g * 4 + sl;
  const long base = (long)b * 2048 + g * 512;
  __shared__ __align__(16) float sp[512];
  __shared__ __align__(16) float upd[512];   // nx = num/den
  __shared__ __align__(16) float upd2[512];  // updates = nx @ Wv; later q1
  __shared__ __align__(16) float lnb[512];
  __shared__ __align__(16) float denred[4];

  if (t < 64) {
    f32x4 dv = *(const f32x4*)(denp + ((long)b * 64 + t) * 16 + g * 4);
    #pragma unroll
    for (int m = 1; m <= 32; m <<= 1) {
      dv[0] += __shfl_xor(dv[0], m); dv[1] += __shfl_xor(dv[1], m);
      dv[2] += __shfl_xor(dv[2], m); dv[3] += __shfl_xor(dv[3], m);
    }
    if (t == 0) *(f32x4*)denred = dv;
  }

  f32x4 hp4 = *(const f32x4*)(sprev + base + t * 4);
  *(f32x4*)(sp + t * 4) = hp4;

  f32x4 ns = {0.f, 0.f, 0.f, 0.f};
  const float* np = nump + (long)b * 131072 + s * 128 + jq;
  #pragma unroll 4
  for (int p = 0; p < 64; ++p) ns += *(const f32x4*)(np + (long)p * 2048);
  __syncthreads();
  *(f32x4*)(upd + t * 4) = ns * (1.f / denred[sl]);
  __syncthreads();

  // updates = nx @ Wv
  f32x4 ud = {0,0,0,0};
  const float* nxr = upd + sl * 128;
  for (int c = 0; c < 128; ++c)
    ud += *(const f32x4*)(Wv + c * 128 + jq) * nxr[c];
  *(f32x4*)(upd2 + t * 4) = ud;
  __syncthreads();

  // GRU
  f32x4 ir = {0,0,0,0}, iz = {0,0,0,0}, inn = {0,0,0,0};
  f32x4 hr = {0,0,0,0}, hz = {0,0,0,0}, hn = {0,0,0,0};
  const float* wih_p = wih + jq;
  const float* whh_p = whh + jq;
  const float* ur  = upd2 + sl * 128;
  const float* hrw = sp + sl * 128;
  for (int c = 0; c < 128; ++c) {
    float u = ur[c], h = hrw[c];
    ir  += *(const f32x4*)(wih_p + c * 384)       * u;
    iz  += *(const f32x4*)(wih_p + c * 384 + 128) * u;
    inn += *(const f32x4*)(wih_p + c * 384 + 256) * u;
    hr  += *(const f32x4*)(whh_p + c * 384)       * h;
    hz  += *(const f32x4*)(whh_p + c * 384 + 128) * h;
    hn  += *(const f32x4*)(whh_p + c * 384 + 256) * h;
  }
  ir  += *(const f32x4*)(bih + jq);
  iz  += *(const f32x4*)(bih + 128 + jq);
  inn += *(const f32x4*)(bih + 256 + jq);
  hr  += *(const f32x4*)(bhh + jq);
  hz  += *(const f32x4*)(bhh + 128 + jq);
  hn  += *(const f32x4*)(bhh + 256 + jq);
  f32x4 snew;
  #pragma unroll
  for (int i = 0; i < 4; ++i) {
    float r = sigf(ir[i] + hr[i]);
    float z = sigf(iz[i] + hz[i]);
    float n = tanhfast(inn[i] + r * hn[i]);
    snew[i] = (1.f - z) * n + z * hp4[i];
  }

  float ps = snew[0] + snew[1] + snew[2] + snew[3];
  float pq = snew[0]*snew[0] + snew[1]*snew[1] + snew[2]*snew[2] + snew[3]*snew[3];
  ps += __shfl_xor(ps, 1); ps += __shfl_xor(ps, 2); ps += __shfl_xor(ps, 4); ps += __shfl_xor(ps, 8); ps += __shfl_xor(ps, 16);
  pq += __shfl_xor(pq, 1); pq += __shfl_xor(pq, 2); pq += __shfl_xor(pq, 4); pq += __shfl_xor(pq, 8); pq += __shfl_xor(pq, 16);
  float mean = ps * (1.f / 128.f);
  float var  = pq * (1.f / 128.f) - mean * mean;
  float rstd = rsqrtf(var + 1e-5f);
  f32x4 lf = (snew - mean) * rstd * (*(const f32x4*)(lnfg + jq)) + (*(const f32x4*)(lnfb + jq));
  *(f32x4*)(lnb + t * 4) = lf;
  __syncthreads();

  f32x4 ha = {0,0,0,0};
  const float* w1p = w1 + jq;
  const float* lrow = lnb + sl * 128;
  for (int c = 0; c < 128; ++c)
    ha += *(const f32x4*)(w1p + c * 128) * lrow[c];
  ha += *(const f32x4*)(b1 + jq);
  #pragma unroll
  for (int i = 0; i < 4; ++i) ha[i] = fmaxf(ha[i], 0.f);
  *(f32x4*)(upd + t * 4) = ha;
  __syncthreads();

  f32x4 oa = {0,0,0,0};
  const float* w2p = w2 + jq;
  const float* hrow = upd + sl * 128;
  for (int c = 0; c < 128; ++c)
    oa += *(const f32x4*)(w2p + c * 128) * hrow[c];
  oa += *(const f32x4*)(b2 + jq);
  f32x4 sf = snew + oa;
  *(f32x4*)(sout + base + t * 4) = sf;

  if (doq) {
    float qs = sf[0] + sf[1] + sf[2] + sf[3];
    float qz = sf[0]*sf[0] + sf[1]*sf[1] + sf[2]*sf[2] + sf[3]*sf[3];
    qs += __shfl_xor(qs, 1); qs += __shfl_xor(qs, 2); qs += __shfl_xor(qs, 4); qs += __shfl_xor(qs, 8); qs += __shfl_xor(qs, 16);
    qz += __shfl_xor(qz, 1); qz += __shfl_xor(qz, 2); qz += __shfl_xor(qz, 4); qz += __shfl_xor(qz, 8); qz += __shfl_xor(qz, 16);
    float m2 = qs * (1.f / 128.f);
    float v2 = qz * (1.f / 128.f) - m2 * m2;
    float rs2 = rsqrtf(v2 + 1e-5f);
    f32x4 lq = (sf - m2) * rs2 * (*(const f32x4*)(lnsg + jq)) + (*(const f32x4*)(lnsb + jq));
    *(f32x4*)(sp + t * 4) = lq;   // sp dead after GRU
    __syncthreads();
    f32x4 q1 = {0,0,0,0};
    const float* qrow = sp + sl * 128;
    for (int c = 0; c < 128; ++c)
      q1 += *(const f32x4*)(Wq + c * 128 + jq) * qrow[c];
    *(f32x4*)(upd2 + t * 4) = q1;
    __syncthreads();
    const float* q1r = upd2 + sl * 128;
    f32x4 qa = {0,0,0,0};
    for (int c2 = 0; c2 < 128; c2 += 4) {
      f32x4 qv = *(const f32x4*)(q1r + c2);
      #pragma unroll
      for (int i = 0; i < 4; ++i) {
        f32x4 wv = *(const f32x4*)(Wk + (jq + i) * 128 + c2);
        qa[i] += qv[0]*wv[0] + qv[1]*wv[1] + qv[2]*wv[2] + qv[3]*wv[3];
      }
    }
    qa *= 0.08838834764831845f;
    u32x2 pk = { pkbf(qa[0], qa[1]), pkbf(qa[2], qa[3]) };
    *(u32x2*)(qout + base + t * 4) = pk;
  }
}

extern "C" void kernel_launch(void* const* d_in, const int* in_sizes, int n_in,
                              void* d_out, int out_size, void* d_ws, size_t ws_size,
                              hipStream_t stream) {
  (void)in_sizes; (void)n_in; (void)out_size; (void)ws_size;
  const float* slots = (const float*)d_in[0];
  const float* inputs = (const float*)d_in[1];
  const float* Wq  = (const float*)d_in[2];
  const float* Wk  = (const float*)d_in[3];
  const float* Wv  = (const float*)d_in[4];
  const float* wih = (const float*)d_in[5];
  const float* whh = (const float*)d_in[6];
  const float* bih = (const float*)d_in[7];
  const float* bhh = (const float*)d_in[8];
  const float* w1  = (const float*)d_in[9];
  const float* b1  = (const float*)d_in[10];
  const float* w2  = (const float*)d_in[11];
  const float* b2  = (const float*)d_in[12];
  const float* lnig = (const float*)d_in[13];
  const float* lnib = (const float*)d_in[14];
  const float* lnsg = (const float*)d_in[15];
  const float* lnsb = (const float*)d_in[16];
  const float* lnfg = (const float*)d_in[17];
  const float* lnfb = (const float*)d_in[18];

  char* ws = (char*)d_ws;
  unsigned short* xln  = (unsigned short*)(ws);
  unsigned short* qbuf = (unsigned short*)(ws + 134217728L);
  float* nump = (float*)(ws + 134348800L);
  float* denp = (float*)(ws + 151126016L);
  float* sbuf = (float*)(ws + 151257088L);

  kq_init<<<32, 512, 0, stream>>>(slots, lnsg, lnsb, Wq, Wk, qbuf);
  for (int it = 0; it < 3; ++it) {
    if (it == 0)
      k2_attn<1><<<dim3(32, 32), 256, 0, stream>>>(inputs, lnig, lnib, xln,
                                                   qbuf, nump, denp);
    else
      k2_attn<0><<<dim3(32, 32), 256, 0, stream>>>(inputs, lnig, lnib, xln,
                                                   qbuf, nump, denp);
    const float* sprev = (it == 0) ? slots : sbuf;
    float* sdst = (it == 2) ? (float*)d_out : sbuf;
    k3_update<<<dim3(4, 32), 128, 0, stream>>>(sprev, nump, denp, Wv,
                                      wih, whh, bih, bhh, w1, b1, w2, b2,
                                      lnfg, lnfb, lnsg, lnsb, Wq, Wk,
                                      sdst, qbuf, (it < 2) ? 1 : 0);
  }
}

// Round 14
// 346.843 us; speedup vs baseline: 1.0625x; 1.0625x over previous
//
#include <hip/hip_runtime.h>

// SlotAttention MI355X v14 — v12 (349us, proven) with ONE change: k2's global
// loads coalesced. Each wave's 32n x 128c tile is contiguous 8KB in xln; load
// it lane-linear (8 x b128, 1KB/instr) -> LDS bounce (lane-linear write,
// swizzled b128 frag reads key 16*(lr^(row&15))) -> then identical v12 flow
// (same buffer reused as xT). v12's scattered loads hit 16 segments/instr
// (~2.2 TB/s); this gets 1 segment/instr.
// Workspace (~151.6 MiB): xln@0, qbuf@134217728, wqk@134348800,
//   nump@134414336 (16.8MB), denp@151191552, sbuf@151322624.

#define NTOT 16384
#define CDIM 128

using short8 = __attribute__((ext_vector_type(8))) short;
using f32x4  = __attribute__((ext_vector_type(4))) float;
using u32x2  = __attribute__((ext_vector_type(2))) unsigned;

__device__ __forceinline__ unsigned pkbf(float lo, float hi) {
  unsigned r;
  asm("v_cvt_pk_bf16_f32 %0, %1, %2" : "=v"(r) : "v"(lo), "v"(hi));
  return r;
}
__device__ __forceinline__ float sigf(float x) { return 1.f / (1.f + __expf(-x)); }
__device__ __forceinline__ float tanhfast(float x) {
  x = fminf(fmaxf(x, -15.f), 15.f);
  float e = __expf(2.f * x);
  return (e - 1.f) / (e + 1.f);
}

// ---- K0: Wqk[cq][ck] = sum_c2 Wq[cq][c2] * Wk[ck][c2]  (= Wq @ Wk^T) ----
__global__ __launch_bounds__(256) void k0_wqk(const float* __restrict__ Wq,
    const float* __restrict__ Wk, float* __restrict__ wqk) {
  int idx = blockIdx.x * 256 + threadIdx.x;  // 16384
  int cq = idx >> 7, ck = idx & 127;
  const float* a = Wq + cq * 128;
  const float* b = Wk + ck * 128;
  float s = 0.f;
  #pragma unroll 8
  for (int i = 0; i < 128; i += 4) {
    f32x4 av = *(const f32x4*)(a + i), bv = *(const f32x4*)(b + i);
    s += av[0]*bv[0] + av[1]*bv[1] + av[2]*bv[2] + av[3]*bv[3];
  }
  wqk[idx] = s;
}

// ---- K1: pure LayerNorm stream: x f32 -> xln bf16 [b][n][c] row-major ----
__global__ __launch_bounds__(256) void k1_ln(const float* __restrict__ in,
    const float* __restrict__ gam, const float* __restrict__ bet,
    unsigned short* __restrict__ xln) {
  __shared__ __align__(16) unsigned short xb[64 * 136];  // pad 8 -> 272B rows
  __shared__ float gs[128], bs[128];
  const int t = threadIdx.x, w = t >> 6, l = t & 63, lr = l & 15, lg = l >> 4;
  if (t < 128) { gs[t] = gam[t]; bs[t] = bet[t]; }
  const long rowbase = (long)blockIdx.x * 64;
  const float* src = in + (rowbase + w * 16 + lr) * CDIM;
  f32x4 x[4][2];
  #pragma unroll
  for (int kb = 0; kb < 4; ++kb) {
    x[kb][0] = *(const f32x4*)(src + kb * 32 + lg * 8);
    x[kb][1] = *(const f32x4*)(src + kb * 32 + lg * 8 + 4);
  }
  float s1 = 0.f, s2 = 0.f;
  #pragma unroll
  for (int kb = 0; kb < 4; ++kb)
    #pragma unroll
    for (int h = 0; h < 2; ++h)
      #pragma unroll
      for (int i = 0; i < 4; ++i) { float xx = x[kb][h][i]; s1 += xx; s2 += xx * xx; }
  s1 += __shfl_xor(s1, 16); s1 += __shfl_xor(s1, 32);
  s2 += __shfl_xor(s2, 16); s2 += __shfl_xor(s2, 32);
  const float mean = s1 * (1.f / 128.f);
  const float rstd = rsqrtf(s2 * (1.f / 128.f) - mean * mean + 1e-5f);
  __syncthreads();  // gs/bs ready
  #pragma unroll
  for (int kb = 0; kb < 4; ++kb) {
    int c0 = kb * 32 + lg * 8;
    union { unsigned uw[4]; short8 s8; } cv;
    #pragma unroll
    for (int p = 0; p < 2; ++p) {
      float y0 = (x[kb][p][0] - mean) * rstd * gs[c0 + p*4 + 0] + bs[c0 + p*4 + 0];
      float y1 = (x[kb][p][1] - mean) * rstd * gs[c0 + p*4 + 1] + bs[c0 + p*4 + 1];
      float y2 = (x[kb][p][2] - mean) * rstd * gs[c0 + p*4 + 2] + bs[c0 + p*4 + 2];
      float y3 = (x[kb][p][3] - mean) * rstd * gs[c0 + p*4 + 3] + bs[c0 + p*4 + 3];
      cv.uw[p*2 + 0] = pkbf(y0, y1);
      cv.uw[p*2 + 1] = pkbf(y2, y3);
    }
    *(short8*)(xb + (w * 16 + lr) * 136 + c0) = cv.s8;
  }
  asm volatile("" ::: "memory");  // same-wave LDS RAW
  unsigned short* dst = xln + (rowbase + w * 16) * CDIM;
  #pragma unroll
  for (int i = 0; i < 4; ++i) {
    int row = i * 4 + (l >> 4), cb = (l & 15) * 8;
    short8 v = *(const short8*)(xb + (w * 16 + row) * 136 + cb);
    *(short8*)(dst + row * CDIM + cb) = v;  // 1KB contiguous per instr
  }
}

// ---- Kq: qa = (LN_s(slots) @ Wqk) / sqrt(C) -> bf16 [b][16][128] ----
__global__ __launch_bounds__(512) void kq_init(
    const float* __restrict__ slots, const float* __restrict__ lnsg,
    const float* __restrict__ lnsb, const float* __restrict__ wqk,
    unsigned short* __restrict__ qout) {
  const int b = blockIdx.x, t = threadIdx.x;
  const int s = t >> 5, jq = (t & 31) * 4;
  __shared__ __align__(16) float lnq[2048];
  f32x4 x4 = *(const f32x4*)(slots + b * 2048 + t * 4);
  float ps = x4[0] + x4[1] + x4[2] + x4[3];
  float pq = x4[0]*x4[0] + x4[1]*x4[1] + x4[2]*x4[2] + x4[3]*x4[3];
  ps += __shfl_xor(ps, 1); ps += __shfl_xor(ps, 2); ps += __shfl_xor(ps, 4); ps += __shfl_xor(ps, 8); ps += __shfl_xor(ps, 16);
  pq += __shfl_xor(pq, 1); pq += __shfl_xor(pq, 2); pq += __shfl_xor(pq, 4); pq += __shfl_xor(pq, 8); pq += __shfl_xor(pq, 16);
  float mean = ps * (1.f / 128.f);
  float var  = pq * (1.f / 128.f) - mean * mean;
  float rstd = rsqrtf(var + 1e-5f);
  f32x4 l4 = (x4 - mean) * rstd * (*(const f32x4*)(lnsg + jq)) + (*(const f32x4*)(lnsb + jq));
  *(f32x4*)(lnq + t * 4) = l4;
  __syncthreads();
  f32x4 qa = {0.f, 0.f, 0.f, 0.f};
  const float* wqp = wqk + jq;
  const float* qrow = lnq + s * 128;
  for (int c = 0; c < 128; ++c)
    qa += *(const f32x4*)(wqp + c * 128) * qrow[c];
  qa *= 0.08838834764831845f;  // 1/sqrt(128)
  u32x2 pk = { pkbf(qa[0], qa[1]), pkbf(qa[2], qa[3]) };
  *(u32x2*)(qout + b * 2048 + t * 4) = pk;
}

// ---- K2: coalesced stage -> LDS bounce -> dots -> softmax -> p @ xln ----
__global__ __launch_bounds__(256) void k2_attn(
    const unsigned short* __restrict__ xln, const unsigned short* __restrict__ qm,
    float* __restrict__ nump, float* __restrict__ denp) {
  const int nb = blockIdx.x, b = blockIdx.y;
  const int t = threadIdx.x, w = t >> 6, l = t & 63, lr = l & 15, lg = l >> 4;
  // smem: per-wave 8KB buffer (tile stage, then xT) x4 | pbuf 4x1.25KB
  __shared__ __align__(16) char smem[38912];
  char* T = smem + w * 8192;
  unsigned short* pbw = (unsigned short*)(smem + 32768) + w * 640;

  const unsigned short* xb = xln + (long)b * (NTOT * CDIM);
  const unsigned short* qb = qm + b * 2048;

  short8 qf[4];
  #pragma unroll
  for (int kk = 0; kk < 4; ++kk)
    qf[kk] = *(const short8*)(qb + lr * CDIM + kk * 32 + lg * 8);

  f32x4 acc[8];
  #pragma unroll
  for (int i = 0; i < 8; ++i) acc[i] = (f32x4){0.f, 0.f, 0.f, 0.f};
  f32x4 dacc = {0.f, 0.f, 0.f, 0.f};

  // wave's tile itt starts at n = nb*512 + (itt*4+w)*32; tile = contiguous 8KB
  short8 g[2][8];
  {
    const unsigned short* ts = xb + (long)(nb * 512 + w * 32) * 128 + l * 8;
    #pragma unroll
    for (int k = 0; k < 8; ++k) g[0][k] = *(const short8*)(ts + k * 512);
  }

  #pragma unroll
  for (int it = 0; it < 4; ++it) {
    const int cur = it & 1;
    // stage: lane-linear data -> [n_loc][c] rows with frag-read swizzle.
    // lane holds n_loc = k*4+lg, c = lr*8..+7; addr = n_loc*256 + 16*(lr ^ (n_loc&15))
    #pragma unroll
    for (int k = 0; k < 8; ++k) {
      const unsigned nl = (unsigned)(k * 4 + lg);
      unsigned wr = nl * 256 + ((((unsigned)lr) ^ (nl & 15u)) << 4);
      *(short8*)(T + wr) = g[cur][k];
    }
    // prefetch next tile (overlaps all LDS/MFMA below)
    if (it < 3) {
      const unsigned short* ts = xb + (long)(nb * 512 + ((it + 1) * 4 + w) * 32) * 128 + l * 8;
      #pragma unroll
      for (int k = 0; k < 8; ++k) g[cur ^ 1][k] = *(const short8*)(ts + k * 512);
    }
    asm volatile("" ::: "memory");  // stage writes before frag reads (same-wave in-order)
    // frag reads: row = h*16+lr, c-chunk kk*64+lg*16 bytes, same swizzle (row&15 = lr)
    short8 xcur[8];
    #pragma unroll
    for (int h = 0; h < 2; ++h)
      #pragma unroll
      for (int kk = 0; kk < 4; ++kk) {
        unsigned rd = (unsigned)((h * 16 + lr) * 256) +
                      ((((unsigned)(kk * 4 + lg)) ^ (unsigned)lr) << 4);
        xcur[h * 4 + kk] = *(const short8*)(T + rd);
      }
    // transpose into xT (overwrites T; xcur regs hold the data):
    // byte(c,n) = c*64 + n*2, key (((c>>1)^(c>>3))&3)<<4 -> write key ((e>>1)&3 ^ lg)<<4
    #pragma unroll
    for (int r = 0; r < 8; ++r) {
      const int h = r >> 2, kk = r & 3;
      const unsigned wb = (unsigned)(kk * 2048 + lg * 512 + (h * 16 + lr) * 2);
      #pragma unroll
      for (int e = 0; e < 8; ++e) {
        unsigned key = ((((unsigned)e >> 1) & 3u) ^ (unsigned)lg) << 4;
        unsigned off = (wb + e * 64) ^ key;
        *(unsigned short*)(T + off) = (unsigned short)xcur[r][e];
      }
    }
    // dots: D[s][n] per 16-n half
    #pragma unroll
    for (int h = 0; h < 2; ++h) {
      f32x4 d = {0.f, 0.f, 0.f, 0.f};
      #pragma unroll
      for (int kk = 0; kk < 4; ++kk)
        d = __builtin_amdgcn_mfma_f32_16x16x32_bf16(qf[kk], xcur[h*4+kk], d, 0, 0, 0);
      float e0 = __expf(d[0]), e1 = __expf(d[1]), e2 = __expf(d[2]), e3 = __expf(d[3]);
      float cs = e0 + e1 + e2 + e3;
      cs += __shfl_xor(cs, 16);
      cs += __shfl_xor(cs, 32);
      float inv = 1.f / cs;
      float p0 = e0 * inv + 1e-8f, p1 = e1 * inv + 1e-8f,
            p2 = e2 * inv + 1e-8f, p3 = e3 * inv + 1e-8f;
      dacc[0] += p0; dacc[1] += p1; dacc[2] += p2; dacc[3] += p3;
      unsigned w01 = pkbf(p0, p1), w23 = pkbf(p2, p3);
      const int nn = h * 16 + lr;
      pbw[(lg*4 + 0) * 40 + nn] = (unsigned short)w01;
      pbw[(lg*4 + 1) * 40 + nn] = (unsigned short)(w01 >> 16);
      pbw[(lg*4 + 2) * 40 + nn] = (unsigned short)w23;
      pbw[(lg*4 + 3) * 40 + nn] = (unsigned short)(w23 >> 16);
    }
    asm volatile("" ::: "memory");  // xT/pbuf writes before reads
    short8 pf = *(const short8*)(pbw + lr * 40 + lg * 8);  // B-frag col=s, k=n
    #pragma unroll
    for (int ct = 0; ct < 8; ++ct) {
      // read key for c=ct*16+lr: ((lr>>1)&3) ^ ((ct*2 + (lr>>3))&3)
      unsigned key = (((((unsigned)lr >> 1) & 3u) ^
                      (((unsigned)(ct * 2) + ((unsigned)lr >> 3)) & 3u)) << 4);
      unsigned off = ((unsigned)((ct*16 + lr) * 64 + lg * 16)) ^ key;
      short8 af = *(const short8*)(T + off);
      acc[ct] = __builtin_amdgcn_mfma_f32_16x16x32_bf16(af, pf, acc[ct], 0, 0, 0);
    }
    asm volatile("" ::: "memory");  // PV reads before next tile's stage writes
  }

  // den: reduce over n (lr lanes); all lanes end with den for s=lg*4+r
  #pragma unroll
  for (int m = 1; m <= 8; m <<= 1) {
    dacc[0] += __shfl_xor(dacc[0], m); dacc[1] += __shfl_xor(dacc[1], m);
    dacc[2] += __shfl_xor(dacc[2], m); dacc[3] += __shfl_xor(dacc[3], m);
  }
  __syncthreads();  // all waves done with T/pbuf
  if (w >= 2) {
    float* rb = (float*)(smem + (w - 2) * 8192);
    #pragma unroll
    for (int ct = 0; ct < 8; ++ct)
      *(f32x4*)(rb + lr * 128 + ct * 16 + lg * 4) = acc[ct];
    if (lr == 0) {
      float* db = (float*)(smem + 32768) + (w - 2) * 16;
      #pragma unroll
      for (int r = 0; r < 4; ++r) db[lg * 4 + r] = dacc[r];
    }
  }
  __syncthreads();
  if (w < 2) {
    const float* rb = (float*)(smem + w * 8192);
    float* outp = nump + (((long)b * 32 + nb) * 2 + w) * 2048;
    #pragma unroll
    for (int ct = 0; ct < 8; ++ct) {
      f32x4 other = *(const f32x4*)(rb + lr * 128 + ct * 16 + lg * 4);
      *(f32x4*)(outp + lr * 128 + ct * 16 + lg * 4) = acc[ct] + other;  // [s][c]
    }
    if (lr == 0) {
      const float* db = (float*)(smem + 32768) + w * 16;
      #pragma unroll
      for (int r = 0; r < 4; ++r)
        denp[(((long)b * 32 + nb) * 2 + w) * 16 + lg * 4 + r] =
            dacc[r] + db[lg * 4 + r];
    }
  }
}

// ---- K3: reduce(64) -> /den -> @Wv -> GRU -> MLP -> slots (+ qa next) ----
__global__ __launch_bounds__(128) void k3_update(
    const float* __restrict__ sprev, const float* __restrict__ nump,
    const float* __restrict__ denp, const float* __restrict__ Wv,
    const float* __restrict__ wih, const float* __restrict__ whh,
    const float* __restrict__ bih, const float* __restrict__ bhh,
    const float* __restrict__ w1, const float* __restrict__ b1,
    const float* __restrict__ w2, const float* __restrict__ b2,
    const float* __restrict__ lnfg, const float* __restrict__ lnfb,
    const float* __restrict__ lnsg, const float* __restrict__ lnsb,
    const float* __restrict__ wqk,
    float* __restrict__ sout, unsigned short* __restrict__ qout, const int doq) {
  const int g = blockIdx.x, b = blockIdx.y, t = threadIdx.x;
  const int sl = t >> 5, jq = (t & 31) * 4;
  const int s = g * 4 + sl;
  const long base = (long)b * 2048 + g * 512;
  __shared__ __align__(16) float sp[512];
  __shared__ __align__(16) float upd[512];   // nx = num/den
  __shared__ __align__(16) float upd2[512];  // updates = nx @ Wv
  __shared__ __align__(16) float lnb[512];
  __shared__ __align__(16) float denred[4];

  if (t < 64) {
    f32x4 dv = *(const f32x4*)(denp + ((long)b * 64 + t) * 16 + g * 4);
    #pragma unroll
    for (int m = 1; m <= 32; m <<= 1) {
      dv[0] += __shfl_xor(dv[0], m); dv[1] += __shfl_xor(dv[1], m);
      dv[2] += __shfl_xor(dv[2], m); dv[3] += __shfl_xor(dv[3], m);
    }
    if (t == 0) *(f32x4*)denred = dv;
  }

  f32x4 hp4 = *(const f32x4*)(sprev + base + t * 4);
  *(f32x4*)(sp + t * 4) = hp4;

  f32x4 ns = {0.f, 0.f, 0.f, 0.f};
  const float* np = nump + (long)b * 131072 + s * 128 + jq;
  #pragma unroll 4
  for (int p = 0; p < 64; ++p) ns += *(const f32x4*)(np + (long)p * 2048);
  __syncthreads();
  *(f32x4*)(upd + t * 4) = ns * (1.f / denred[sl]);
  __syncthreads();

  // updates = nx @ Wv
  f32x4 ud = {0,0,0,0};
  const float* nxr = upd + sl * 128;
  for (int c = 0; c < 128; ++c)
    ud += *(const f32x4*)(Wv + c * 128 + jq) * nxr[c];
  *(f32x4*)(upd2 + t * 4) = ud;
  __syncthreads();

  // GRU
  f32x4 ir = {0,0,0,0}, iz = {0,0,0,0}, inn = {0,0,0,0};
  f32x4 hr = {0,0,0,0}, hz = {0,0,0,0}, hn = {0,0,0,0};
  const float* wih_p = wih + jq;
  const float* whh_p = whh + jq;
  const float* ur  = upd2 + sl * 128;
  const float* hrw = sp + sl * 128;
  for (int c = 0; c < 128; ++c) {
    float u = ur[c], h = hrw[c];
    ir  += *(const f32x4*)(wih_p + c * 384)       * u;
    iz  += *(const f32x4*)(wih_p + c * 384 + 128) * u;
    inn += *(const f32x4*)(wih_p + c * 384 + 256) * u;
    hr  += *(const f32x4*)(whh_p + c * 384)       * h;
    hz  += *(const f32x4*)(whh_p + c * 384 + 128) * h;
    hn  += *(const f32x4*)(whh_p + c * 384 + 256) * h;
  }
  ir  += *(const f32x4*)(bih + jq);
  iz  += *(const f32x4*)(bih + 128 + jq);
  inn += *(const f32x4*)(bih + 256 + jq);
  hr  += *(const f32x4*)(bhh + jq);
  hz  += *(const f32x4*)(bhh + 128 + jq);
  hn  += *(const f32x4*)(bhh + 256 + jq);
  f32x4 snew;
  #pragma unroll
  for (int i = 0; i < 4; ++i) {
    float r = sigf(ir[i] + hr[i]);
    float z = sigf(iz[i] + hz[i]);
    float n = tanhfast(inn[i] + r * hn[i]);
    snew[i] = (1.f - z) * n + z * hp4[i];
  }

  float ps = snew[0] + snew[1] + snew[2] + snew[3];
  float pq = snew[0]*snew[0] + snew[1]*snew[1] + snew[2]*snew[2] + snew[3]*snew[3];
  ps += __shfl_xor(ps, 1); ps += __shfl_xor(ps, 2); ps += __shfl_xor(ps, 4); ps += __shfl_xor(ps, 8); ps += __shfl_xor(ps, 16);
  pq += __shfl_xor(pq, 1); pq += __shfl_xor(pq, 2); pq += __shfl_xor(pq, 4); pq += __shfl_xor(pq, 8); pq += __shfl_xor(pq, 16);
  float mean = ps * (1.f / 128.f);
  float var  = pq * (1.f / 128.f) - mean * mean;
  float rstd = rsqrtf(var + 1e-5f);
  f32x4 lf = (snew - mean) * rstd * (*(const f32x4*)(lnfg + jq)) + (*(const f32x4*)(lnfb + jq));
  *(f32x4*)(lnb + t * 4) = lf;
  __syncthreads();

  f32x4 ha = {0,0,0,0};
  const float* w1p = w1 + jq;
  const float* lrow = lnb + sl * 128;
  for (int c = 0; c < 128; ++c)
    ha += *(const f32x4*)(w1p + c * 128) * lrow[c];
  ha += *(const f32x4*)(b1 + jq);
  #pragma unroll
  for (int i = 0; i < 4; ++i) ha[i] = fmaxf(ha[i], 0.f);
  *(f32x4*)(upd + t * 4) = ha;
  __syncthreads();

  f32x4 oa = {0,0,0,0};
  const float* w2p = w2 + jq;
  const float* hrow = upd + sl * 128;
  for (int c = 0; c < 128; ++c)
    oa += *(const f32x4*)(w2p + c * 128) * hrow[c];
  oa += *(const f32x4*)(b2 + jq);
  f32x4 sf = snew + oa;
  *(f32x4*)(sout + base + t * 4) = sf;

  if (doq) {
    float qs = sf[0] + sf[1] + sf[2] + sf[3];
    float qz = sf[0]*sf[0] + sf[1]*sf[1] + sf[2]*sf[2] + sf[3]*sf[3];
    qs += __shfl_xor(qs, 1); qs += __shfl_xor(qs, 2); qs += __shfl_xor(qs, 4); qs += __shfl_xor(qs, 8); qs += __shfl_xor(qs, 16);
    qz += __shfl_xor(qz, 1); qz += __shfl_xor(qz, 2); qz += __shfl_xor(qz, 4); qz += __shfl_xor(qz, 8); qz += __shfl_xor(qz, 16);
    float m2 = qs * (1.f / 128.f);
    float v2 = qz * (1.f / 128.f) - m2 * m2;
    float rs2 = rsqrtf(v2 + 1e-5f);
    f32x4 lq = (sf - m2) * rs2 * (*(const f32x4*)(lnsg + jq)) + (*(const f32x4*)(lnsb + jq));
    *(f32x4*)(sp + t * 4) = lq;
    __syncthreads();
    f32x4 qa = {0,0,0,0};
    const float* wqp = wqk + jq;
    const float* qrow = sp + sl * 128;
    for (int c = 0; c < 128; ++c)
      qa += *(const f32x4*)(wqp + c * 128) * qrow[c];
    qa *= 0.08838834764831845f;
    u32x2 pk = { pkbf(qa[0], qa[1]), pkbf(qa[2], qa[3]) };
    *(u32x2*)(qout + base + t * 4) = pk;
  }
}

extern "C" void kernel_launch(void* const* d_in, const int* in_sizes, int n_in,
                              void* d_out, int out_size, void* d_ws, size_t ws_size,
                              hipStream_t stream) {
  (void)in_sizes; (void)n_in; (void)out_size; (void)ws_size;
  const float* slots = (const float*)d_in[0];
  const float* inputs = (const float*)d_in[1];
  const float* Wq  = (const float*)d_in[2];
  const float* Wk  = (const float*)d_in[3];
  const float* Wv  = (const float*)d_in[4];
  const float* wih = (const float*)d_in[5];
  const float* whh = (const float*)d_in[6];
  const float* bih = (const float*)d_in[7];
  const float* bhh = (const float*)d_in[8];
  const float* w1  = (const float*)d_in[9];
  const float* b1  = (const float*)d_in[10];
  const float* w2  = (const float*)d_in[11];
  const float* b2  = (const float*)d_in[12];
  const float* lnig = (const float*)d_in[13];
  const float* lnib = (const float*)d_in[14];
  const float* lnsg = (const float*)d_in[15];
  const float* lnsb = (const float*)d_in[16];
  const float* lnfg = (const float*)d_in[17];
  const float* lnfb = (const float*)d_in[18];

  char* ws = (char*)d_ws;
  unsigned short* xln  = (unsigned short*)(ws);
  unsigned short* qbuf = (unsigned short*)(ws + 134217728L);
  float* wqk  = (float*)(ws + 134348800L);
  float* nump = (float*)(ws + 134414336L);
  float* denp = (float*)(ws + 151191552L);
  float* sbuf = (float*)(ws + 151322624L);

  k0_wqk<<<64, 256, 0, stream>>>(Wq, Wk, wqk);
  k1_ln<<<8192, 256, 0, stream>>>(inputs, lnig, lnib, xln);
  kq_init<<<32, 512, 0, stream>>>(slots, lnsg, lnsb, wqk, qbuf);
  for (int it = 0; it < 3; ++it) {
    k2_attn<<<dim3(32, 32), 256, 0, stream>>>(xln, qbuf, nump, denp);
    const float* sprev = (it == 0) ? slots : sbuf;
    float* sdst = (it == 2) ? (float*)d_out : sbuf;
    k3_update<<<dim3(4, 32), 128, 0, stream>>>(sprev, nump, denp, Wv,
                                      wih, whh, bih, bhh, w1, b1, w2, b2,
                                      lnfg, lnfb, lnsg, lnsb, wqk,
                                      sdst, qbuf, (it < 2) ? 1 : 0);
  }
}